// Round 6
// baseline (187.211 us; speedup 1.0000x reference)
//
#include <hip/hip_runtime.h>
#include <math.h>

#define D 20
#define NT 256
#define RPT 2  // rows per thread

// ws word offsets (float4-aligned):
//   [0..3]     acc[0]=sum_h, acc[1]=sum_abs (doubles)
//   [8..407]   M1tT[400]: [d][j] = sum_e W[e][d]*W_init[e][j]   (d-major)
//   [408..427] c[20]:     c[j] = sum_e b[e]*W_init[e][j] + 1
//   [428..827] Wt[400]:   [j][j2] = W[j2][j]                    (transposed)
#define WS_M1_OFF 8
#define WS_C_OFF 408
#define WS_WT_OFF 428

__global__ void prep_kernel(const float* __restrict__ W,
                            const float* __restrict__ b,
                            const float* __restrict__ Wi,
                            float* __restrict__ wsf) {
  int t = threadIdx.x;  // 1024 threads
  if (t < D * D) {
    int d = t / D, j = t % D;
    float a = 0.f;
#pragma unroll
    for (int e = 0; e < D; ++e) a = fmaf(W[e * D + d], Wi[e * D + j], a);
    wsf[WS_M1_OFF + t] = a;
  } else if (t < 2 * D * D) {
    int i = t - D * D;
    int j = i / D, j2 = i % D;
    wsf[WS_WT_OFF + i] = W[j2 * D + j];
  } else if (t < 2 * D * D + D) {
    int j = t - 2 * D * D;
    float a = 1.0f;
#pragma unroll
    for (int e = 0; e < D; ++e) a = fmaf(b[e], Wi[e * D + j], a);
    wsf[WS_C_OFF + j] = a;
  } else if (t == 2 * D * D + D) {
    double* acc = (double*)wsf;
    acc[0] = 0.0;
    acc[1] = 0.0;
  }
}

// X: direct per-thread float4 loads, ALL issued upfront (tight window ->
// lines merge in L1/MSHR, no over-fetch; drained at the constants barrier =
// free prefetch). Constants: LDS float4 wave-uniform broadcasts (no
// conflicts, LDS pipe overlaps VALU). Both stages rank-1 with 20 indep
// accumulators per row -> no FMA-latency chains.
__global__ __launch_bounds__(NT, 4) void fused_kernel(
    const float* __restrict__ X,
    const float* __restrict__ b,
    const float* __restrict__ wsf,
    double* __restrict__ acc,
    int nrows) {
  __shared__ __align__(16) float sM[D * D];   // M1tT, d-major
  __shared__ __align__(16) float sWt[D * D];  // W transposed, j-major
  __shared__ __align__(16) float sc[D];
  __shared__ __align__(16) float sb[D];
  __shared__ float sred[8];

  const int t = threadIdx.x;

  const long long row0 = ((long long)blockIdx.x * NT + t) * RPT;
  const long long rmax = (long long)nrows - RPT;
  const float valid = (row0 <= rmax) ? 1.0f : 0.0f;
  const long long r0 = (row0 <= rmax) ? row0 : rmax;

  // --- Issue all 10 X loads immediately (2 rows * 5 float4, contiguous) ---
  const float4* __restrict__ Xv = (const float4*)(X + r0 * D);
  float4 xv[2 * 5];
#pragma unroll
  for (int s = 0; s < 2 * 5; ++s) xv[s] = Xv[s];

  // --- Constants into LDS (cooperative float4) ---
  if (t < 100) {
    ((float4*)sM)[t] = ((const float4*)(wsf + WS_M1_OFF))[t];
  } else if (t < 200) {
    ((float4*)sWt)[t - 100] = ((const float4*)(wsf + WS_WT_OFF))[t - 100];
  } else if (t < 205) {
    ((float4*)sc)[t - 200] = ((const float4*)(wsf + WS_C_OFF))[t - 200];
  } else if (t < 210) {
    ((float4*)sb)[t - 205] = ((const float4*)b)[t - 205];
  }
  __syncthreads();

  // Unpack loaded X into scalar regs.
  float xa[RPT][D];
#pragma unroll
  for (int k = 0; k < RPT; ++k)
#pragma unroll
    for (int jv = 0; jv < 5; ++jv) {
      float4 v = xv[k * 5 + jv];
      xa[k][4 * jv + 0] = v.x;
      xa[k][4 * jv + 1] = v.y;
      xa[k][4 * jv + 2] = v.z;
      xa[k][4 * jv + 3] = v.w;
    }

  // --- Stage 1: h2 = x @ M1 + c (d-major rank-1, 20 indep accs/row) ---
  float h2[RPT][D];
  {
    const float4* cv = (const float4*)sc;
#pragma unroll
    for (int jv = 0; jv < 5; ++jv) {
      float4 cc = cv[jv];
#pragma unroll
      for (int k = 0; k < RPT; ++k) {
        h2[k][4 * jv + 0] = cc.x;
        h2[k][4 * jv + 1] = cc.y;
        h2[k][4 * jv + 2] = cc.z;
        h2[k][4 * jv + 3] = cc.w;
      }
    }
  }
#pragma unroll
  for (int d = 0; d < D; ++d) {
    const float4* mr = (const float4*)&sM[d * D];  // wave-uniform broadcast
    const float x0 = xa[0][d], x1 = xa[1][d];
#pragma unroll
    for (int jv = 0; jv < 5; ++jv) {
      float4 m = mr[jv];
      h2[0][4 * jv + 0] = fmaf(x0, m.x, h2[0][4 * jv + 0]);
      h2[1][4 * jv + 0] = fmaf(x1, m.x, h2[1][4 * jv + 0]);
      h2[0][4 * jv + 1] = fmaf(x0, m.y, h2[0][4 * jv + 1]);
      h2[1][4 * jv + 1] = fmaf(x1, m.y, h2[1][4 * jv + 1]);
      h2[0][4 * jv + 2] = fmaf(x0, m.z, h2[0][4 * jv + 2]);
      h2[1][4 * jv + 2] = fmaf(x1, m.z, h2[1][4 * jv + 2]);
      h2[0][4 * jv + 3] = fmaf(x0, m.w, h2[0][4 * jv + 3]);
      h2[1][4 * jv + 3] = fmaf(x1, m.w, h2[1][4 * jv + 3]);
    }
  }

  // --- Stage 2: h3 = relu(h2) @ W^T + b (j-major rank-1 via Wt) ---
  float h3[RPT][D];
  {
    const float4* bv = (const float4*)sb;
#pragma unroll
    for (int jv = 0; jv < 5; ++jv) {
      float4 bb = bv[jv];
#pragma unroll
      for (int k = 0; k < RPT; ++k) {
        h3[k][4 * jv + 0] = bb.x;
        h3[k][4 * jv + 1] = bb.y;
        h3[k][4 * jv + 2] = bb.z;
        h3[k][4 * jv + 3] = bb.w;
      }
    }
  }
#pragma unroll
  for (int j = 0; j < D; ++j) {
    const float4* wr = (const float4*)&sWt[j * D];  // wave-uniform broadcast
    const float p0 = fmaxf(h2[0][j], 0.f);
    const float p1 = fmaxf(h2[1][j], 0.f);
#pragma unroll
    for (int jv = 0; jv < 5; ++jv) {
      float4 w = wr[jv];
      h3[0][4 * jv + 0] = fmaf(p0, w.x, h3[0][4 * jv + 0]);
      h3[1][4 * jv + 0] = fmaf(p1, w.x, h3[1][4 * jv + 0]);
      h3[0][4 * jv + 1] = fmaf(p0, w.y, h3[0][4 * jv + 1]);
      h3[1][4 * jv + 1] = fmaf(p1, w.y, h3[1][4 * jv + 1]);
      h3[0][4 * jv + 2] = fmaf(p0, w.z, h3[0][4 * jv + 2]);
      h3[1][4 * jv + 2] = fmaf(p1, w.z, h3[1][4 * jv + 2]);
      h3[0][4 * jv + 3] = fmaf(p0, w.w, h3[0][4 * jv + 3]);
      h3[1][4 * jv + 3] = fmaf(p1, w.w, h3[1][4 * jv + 3]);
    }
  }

  // --- Masked per-thread sums (branchless tail) ---
  float rs = 0.f, ra = 0.f;
#pragma unroll
  for (int k = 0; k < RPT; ++k) {
    float s = 0.f, a = 0.f;
#pragma unroll
    for (int j = 0; j < D; ++j) {
      s += h3[k][j];
      a += fabsf(h3[k][j]);
    }
    rs += s;
    ra += a;
  }
  rs *= valid;
  ra *= valid;

  // --- Wave shuffle reduce -> cross-wave LDS -> one fp64 atomic/block ---
#pragma unroll
  for (int off = 32; off > 0; off >>= 1) {
    rs += __shfl_down(rs, off, 64);
    ra += __shfl_down(ra, off, 64);
  }
  const int wave = t >> 6, lane = t & 63;
  if (lane == 0) {
    sred[wave] = rs;
    sred[4 + wave] = ra;
  }
  __syncthreads();
  if (t == 0) {
    float s1 = sred[0] + sred[1] + sred[2] + sred[3];
    float s2 = sred[4] + sred[5] + sred[6] + sred[7];
    atomicAdd(&acc[0], (double)s1);
    atomicAdd(&acc[1], (double)s2);
  }
}

// Single-thread finalize: count halvings of sum(|h|), scale sum(h) by 2^-k.
__global__ void fin_kernel(const double* __restrict__ acc, float* __restrict__ out) {
  double s = acc[1];
  int k = 0;
  while (s > 1.0 && k < 1100) {
    s *= 0.5;
    ++k;
  }
  out[0] = ldexpf((float)acc[0], -k);
}

extern "C" void kernel_launch(void* const* d_in, const int* in_sizes, int n_in,
                              void* d_out, int out_size, void* d_ws, size_t ws_size,
                              hipStream_t stream) {
  const float* X = (const float*)d_in[0];
  const float* W = (const float*)d_in[1];
  const float* b = (const float*)d_in[2];
  const float* Wi = (const float*)d_in[3];
  float* out = (float*)d_out;
  float* wsf = (float*)d_ws;
  double* acc = (double*)d_ws;

  const int nrows = in_sizes[0] / D;  // 1,000,000

  hipLaunchKernelGGL(prep_kernel, dim3(1), dim3(1024), 0, stream, W, b, Wi, wsf);

  const int nthreads = (nrows + RPT - 1) / RPT;
  const int nblocks = (nthreads + NT - 1) / NT;
  hipLaunchKernelGGL(fused_kernel, dim3(nblocks), dim3(NT), 0, stream,
                     X, b, wsf, acc, nrows);

  hipLaunchKernelGGL(fin_kernel, dim3(1), dim3(1), 0, stream, acc, out);
}

// Round 7
// 142.268 us; speedup vs baseline: 1.3159x; 1.3159x over previous
//
#include <hip/hip_runtime.h>
#include <math.h>

#define D 20
#define NT 256
#define RPT 4  // rows per thread

// ws word offsets (16B-aligned):
//   [8..407]    M1tT[400]: [d][j] = sum_e W[e][d]*W_init[e][j]   (d-major)
//   [408..427]  c[20]:     c[j] = sum_e b[e]*W_init[e][j] + 1
//   [428..827]  Wt[400]:   [j][j2] = W[j2][j]                    (transposed)
//   [1024..]    partials: double2 per block (sum, sumabs), nblocks entries
#define WS_M1_OFF 8
#define WS_C_OFF 408
#define WS_WT_OFF 428
#define WS_PART_OFF 1024  // in floats -> byte 4096

__global__ void prep_kernel(const float* __restrict__ W,
                            const float* __restrict__ b,
                            const float* __restrict__ Wi,
                            float* __restrict__ wsf) {
  int t = threadIdx.x;  // 1024 threads
  if (t < D * D) {
    int d = t / D, j = t % D;
    float a = 0.f;
#pragma unroll
    for (int e = 0; e < D; ++e) a = fmaf(W[e * D + d], Wi[e * D + j], a);
    wsf[WS_M1_OFF + t] = a;
  } else if (t < 2 * D * D) {
    int i = t - D * D;
    int j = i / D, j2 = i % D;
    wsf[WS_WT_OFF + i] = W[j2 * D + j];
  } else if (t < 2 * D * D + D) {
    int j = t - 2 * D * D;
    float a = 1.0f;
#pragma unroll
    for (int e = 0; e < D; ++e) a = fmaf(b[e], Wi[e * D + j], a);
    wsf[WS_C_OFF + j] = a;
  }
}

// Constants read via uniform-indexed global loads from __restrict__ args ->
// compiler scalarizes to s_load (SMEM/K$ pipe; separate from VALU/LDS/VMEM).
// X: all 20 float4 loads issued upfront (tight window -> line merging, no
// over-fetch). Both stages rank-1 with 20 independent accumulators per row.
// No atomics: per-block partial sums to distinct slots.
__global__ __launch_bounds__(NT, 2) void fused_kernel(
    const float* __restrict__ X,
    const float* __restrict__ bb_,
    const float* __restrict__ M1,   // d-major [d][j]
    const float* __restrict__ cc_,  // c[j]
    const float* __restrict__ Wt,   // j-major [j][j2]
    double* __restrict__ partials,
    int nrows) {
  const int t = threadIdx.x;

  const long long row0 = ((long long)blockIdx.x * NT + t) * RPT;
  const long long rmax = (long long)nrows - RPT;
  const float valid = (row0 <= rmax) ? 1.0f : 0.0f;
  const long long r0 = (row0 <= rmax) ? row0 : rmax;

  // --- Issue all 20 X float4 loads immediately (4 rows * 5 float4) ---
  const float4* __restrict__ Xv = (const float4*)(X + r0 * D);
  float4 xv[RPT * 5];
#pragma unroll
  for (int s = 0; s < RPT * 5; ++s) xv[s] = Xv[s];

  float xa[RPT][D];
#pragma unroll
  for (int k = 0; k < RPT; ++k)
#pragma unroll
    for (int jv = 0; jv < 5; ++jv) {
      float4 v = xv[k * 5 + jv];
      xa[k][4 * jv + 0] = v.x;
      xa[k][4 * jv + 1] = v.y;
      xa[k][4 * jv + 2] = v.z;
      xa[k][4 * jv + 3] = v.w;
    }

  // --- Stage 1: h2 = x @ M1 + c (d-major rank-1, 20 indep accs/row) ---
  float h2[RPT][D];
#pragma unroll
  for (int j = 0; j < D; ++j) {
    const float cj = cc_[j];  // uniform -> s_load
#pragma unroll
    for (int k = 0; k < RPT; ++k) h2[k][j] = cj;
  }
#pragma unroll
  for (int d = 0; d < D; ++d) {
#pragma unroll
    for (int j = 0; j < D; ++j) {
      const float m = M1[d * D + j];  // uniform -> s_load (chunked dwordx8/16)
      h2[0][j] = fmaf(xa[0][d], m, h2[0][j]);
      h2[1][j] = fmaf(xa[1][d], m, h2[1][j]);
      h2[2][j] = fmaf(xa[2][d], m, h2[2][j]);
      h2[3][j] = fmaf(xa[3][d], m, h2[3][j]);
    }
  }

  // --- ReLU ---
#pragma unroll
  for (int k = 0; k < RPT; ++k)
#pragma unroll
    for (int j = 0; j < D; ++j) h2[k][j] = fmaxf(h2[k][j], 0.f);

  // --- Stage 2: h3 = h2 @ W^T + b (j-major rank-1 via Wt, 20 indep accs/row) ---
  float h3[RPT][D];
#pragma unroll
  for (int j2 = 0; j2 < D; ++j2) {
    const float bj = bb_[j2];  // uniform -> s_load
#pragma unroll
    for (int k = 0; k < RPT; ++k) h3[k][j2] = bj;
  }
#pragma unroll
  for (int j = 0; j < D; ++j) {
#pragma unroll
    for (int j2 = 0; j2 < D; ++j2) {
      const float w = Wt[j * D + j2];  // uniform -> s_load
      h3[0][j2] = fmaf(h2[0][j], w, h3[0][j2]);
      h3[1][j2] = fmaf(h2[1][j], w, h3[1][j2]);
      h3[2][j2] = fmaf(h2[2][j], w, h3[2][j2]);
      h3[3][j2] = fmaf(h2[3][j], w, h3[3][j2]);
    }
  }

  // --- Masked per-thread sums ---
  float rs = 0.f, ra = 0.f;
#pragma unroll
  for (int k = 0; k < RPT; ++k)
#pragma unroll
    for (int j = 0; j < D; ++j) {
      rs += h3[k][j];
      ra += fabsf(h3[k][j]);
    }
  rs *= valid;
  ra *= valid;

  // --- Wave shuffle reduce -> cross-wave LDS -> per-block slot (no atomics) ---
  __shared__ float sred[8];
#pragma unroll
  for (int off = 32; off > 0; off >>= 1) {
    rs += __shfl_down(rs, off, 64);
    ra += __shfl_down(ra, off, 64);
  }
  const int wave = t >> 6, lane = t & 63;
  if (lane == 0) {
    sred[wave] = rs;
    sred[4 + wave] = ra;
  }
  __syncthreads();
  if (t == 0) {
    float s1 = sred[0] + sred[1] + sred[2] + sred[3];
    float s2 = sred[4] + sred[5] + sred[6] + sred[7];
    partials[2 * blockIdx.x + 0] = (double)s1;
    partials[2 * blockIdx.x + 1] = (double)s2;
  }
}

// Reduce per-block partials, count halvings, write scalar output.
__global__ void fin_kernel(const double* __restrict__ partials,
                           float* __restrict__ out, int nblocks) {
  __shared__ double sredh[16], sreda[16];
  const int t = threadIdx.x;  // 1024 threads
  double sh = 0.0, sa = 0.0;
  for (int i = t; i < nblocks; i += 1024) {
    sh += partials[2 * i + 0];
    sa += partials[2 * i + 1];
  }
#pragma unroll
  for (int off = 32; off > 0; off >>= 1) {
    sh += __shfl_down(sh, off, 64);
    sa += __shfl_down(sa, off, 64);
  }
  const int wave = t >> 6, lane = t & 63;
  if (lane == 0) {
    sredh[wave] = sh;
    sreda[wave] = sa;
  }
  __syncthreads();
  if (t == 0) {
    double th = 0.0, ta = 0.0;
#pragma unroll
    for (int w = 0; w < 16; ++w) {
      th += sredh[w];
      ta += sreda[w];
    }
    int k = 0;
    while (ta > 1.0 && k < 1100) {
      ta *= 0.5;
      ++k;
    }
    out[0] = ldexpf((float)th, -k);
  }
}

extern "C" void kernel_launch(void* const* d_in, const int* in_sizes, int n_in,
                              void* d_out, int out_size, void* d_ws, size_t ws_size,
                              hipStream_t stream) {
  const float* X = (const float*)d_in[0];
  const float* W = (const float*)d_in[1];
  const float* b = (const float*)d_in[2];
  const float* Wi = (const float*)d_in[3];
  float* out = (float*)d_out;
  float* wsf = (float*)d_ws;

  const int nrows = in_sizes[0] / D;  // 1,000,000

  hipLaunchKernelGGL(prep_kernel, dim3(1), dim3(1024), 0, stream, W, b, Wi, wsf);

  const int nthreads = (nrows + RPT - 1) / RPT;
  const int nblocks = (nthreads + NT - 1) / NT;  // 977
  double* partials = (double*)(wsf + WS_PART_OFF);
  hipLaunchKernelGGL(fused_kernel, dim3(nblocks), dim3(NT), 0, stream,
                     X, b, wsf + WS_M1_OFF, wsf + WS_C_OFF, wsf + WS_WT_OFF,
                     partials, nrows);

  hipLaunchKernelGGL(fin_kernel, dim3(1), dim3(1024), 0, stream, partials, out,
                     nblocks);
}

// Round 8
// 133.508 us; speedup vs baseline: 1.4023x; 1.0656x over previous
//
#include <hip/hip_runtime.h>
#include <math.h>

#define D 20
#define NT 256
#define RPT 2  // rows per thread

// ws word offsets (16B-aligned):
//   [8..407]    M1tT[400]: [d][j] = sum_e W[e][d]*W_init[e][j]   (d-major)
//   [408..427]  c[20]:     c[j] = sum_e b[e]*W_init[e][j] + 1
//   [428..827]  Wt[400]:   [j][j2] = W[j2][j]                    (transposed)
//   [1024..]    partials: double2 per block (sum, sumabs), nblocks entries
#define WS_M1_OFF 8
#define WS_C_OFF 408
#define WS_WT_OFF 428
#define WS_PART_OFF 1024  // in floats -> byte 4096

__global__ void prep_kernel(const float* __restrict__ W,
                            const float* __restrict__ b,
                            const float* __restrict__ Wi,
                            float* __restrict__ wsf) {
  int t = threadIdx.x;  // 1024 threads
  if (t < D * D) {
    int d = t / D, j = t % D;
    float a = 0.f;
#pragma unroll
    for (int e = 0; e < D; ++e) a = fmaf(W[e * D + d], Wi[e * D + j], a);
    wsf[WS_M1_OFF + t] = a;
  } else if (t < 2 * D * D) {
    int i = t - D * D;
    int j = i / D, j2 = i % D;
    wsf[WS_WT_OFF + i] = W[j2 * D + j];
  } else if (t < 2 * D * D + D) {
    int j = t - 2 * D * D;
    float a = 1.0f;
#pragma unroll
    for (int e = 0; e < D; ++e) a = fmaf(b[e], Wi[e * D + j], a);
    wsf[WS_C_OFF + j] = a;
  }
}

// R7 structure (s_load constants, upfront X loads, rank-1 stages, no atomics)
// with RPT=2: grid 1954 blocks = 7.6 blocks/CU -> up to 30 resident waves/CU
// to hide SMEM-chunk lgkmcnt stalls and the X-load drain. Even if the
// compiler interchanges loops for register pressure, 2 rows give 2
// independent FMA chains = enough to saturate a wave's 2-cyc issue slots.
__global__ __launch_bounds__(NT, 4) void fused_kernel(
    const float* __restrict__ X,
    const float* __restrict__ bb_,
    const float* __restrict__ M1,   // d-major [d][j]
    const float* __restrict__ cc_,  // c[j]
    const float* __restrict__ Wt,   // j-major [j][j2]
    double* __restrict__ partials,
    int nrows) {
  const int t = threadIdx.x;

  const long long row0 = ((long long)blockIdx.x * NT + t) * RPT;
  const long long rmax = (long long)nrows - RPT;
  const float valid = (row0 <= rmax) ? 1.0f : 0.0f;
  const long long r0 = (row0 <= rmax) ? row0 : rmax;

  // --- Issue all 10 X float4 loads immediately (2 rows * 5 float4) ---
  const float4* __restrict__ Xv = (const float4*)(X + r0 * D);
  float4 xv[RPT * 5];
#pragma unroll
  for (int s = 0; s < RPT * 5; ++s) xv[s] = Xv[s];

  float xa[RPT][D];
#pragma unroll
  for (int k = 0; k < RPT; ++k)
#pragma unroll
    for (int jv = 0; jv < 5; ++jv) {
      float4 v = xv[k * 5 + jv];
      xa[k][4 * jv + 0] = v.x;
      xa[k][4 * jv + 1] = v.y;
      xa[k][4 * jv + 2] = v.z;
      xa[k][4 * jv + 3] = v.w;
    }

  // --- Stage 1: h2 = x @ M1 + c (d-major rank-1, 20 indep accs/row) ---
  float h2[RPT][D];
#pragma unroll
  for (int j = 0; j < D; ++j) {
    const float cj = cc_[j];  // uniform -> s_load
#pragma unroll
    for (int k = 0; k < RPT; ++k) h2[k][j] = cj;
  }
#pragma unroll
  for (int d = 0; d < D; ++d) {
#pragma unroll
    for (int j = 0; j < D; ++j) {
      const float m = M1[d * D + j];  // uniform -> s_load
      h2[0][j] = fmaf(xa[0][d], m, h2[0][j]);
      h2[1][j] = fmaf(xa[1][d], m, h2[1][j]);
    }
  }

  // --- ReLU ---
#pragma unroll
  for (int k = 0; k < RPT; ++k)
#pragma unroll
    for (int j = 0; j < D; ++j) h2[k][j] = fmaxf(h2[k][j], 0.f);

  // --- Stage 2: h3 = h2 @ W^T + b (j-major rank-1 via Wt) ---
  float h3[RPT][D];
#pragma unroll
  for (int j2 = 0; j2 < D; ++j2) {
    const float bj = bb_[j2];  // uniform -> s_load
#pragma unroll
    for (int k = 0; k < RPT; ++k) h3[k][j2] = bj;
  }
#pragma unroll
  for (int j = 0; j < D; ++j) {
#pragma unroll
    for (int j2 = 0; j2 < D; ++j2) {
      const float w = Wt[j * D + j2];  // uniform -> s_load
      h3[0][j2] = fmaf(h2[0][j], w, h3[0][j2]);
      h3[1][j2] = fmaf(h2[1][j], w, h3[1][j2]);
    }
  }

  // --- Masked per-thread sums ---
  float rs = 0.f, ra = 0.f;
#pragma unroll
  for (int k = 0; k < RPT; ++k)
#pragma unroll
    for (int j = 0; j < D; ++j) {
      rs += h3[k][j];
      ra += fabsf(h3[k][j]);
    }
  rs *= valid;
  ra *= valid;

  // --- Wave shuffle reduce -> cross-wave LDS -> per-block slot (no atomics) ---
  __shared__ float sred[8];
#pragma unroll
  for (int off = 32; off > 0; off >>= 1) {
    rs += __shfl_down(rs, off, 64);
    ra += __shfl_down(ra, off, 64);
  }
  const int wave = t >> 6, lane = t & 63;
  if (lane == 0) {
    sred[wave] = rs;
    sred[4 + wave] = ra;
  }
  __syncthreads();
  if (t == 0) {
    float s1 = sred[0] + sred[1] + sred[2] + sred[3];
    float s2 = sred[4] + sred[5] + sred[6] + sred[7];
    partials[2 * blockIdx.x + 0] = (double)s1;
    partials[2 * blockIdx.x + 1] = (double)s2;
  }
}

// Reduce per-block partials, count halvings, write scalar output.
__global__ void fin_kernel(const double* __restrict__ partials,
                           float* __restrict__ out, int nblocks) {
  __shared__ double sredh[16], sreda[16];
  const int t = threadIdx.x;  // 1024 threads
  double sh = 0.0, sa = 0.0;
  for (int i = t; i < nblocks; i += 1024) {
    sh += partials[2 * i + 0];
    sa += partials[2 * i + 1];
  }
#pragma unroll
  for (int off = 32; off > 0; off >>= 1) {
    sh += __shfl_down(sh, off, 64);
    sa += __shfl_down(sa, off, 64);
  }
  const int wave = t >> 6, lane = t & 63;
  if (lane == 0) {
    sredh[wave] = sh;
    sreda[wave] = sa;
  }
  __syncthreads();
  if (t == 0) {
    double th = 0.0, ta = 0.0;
#pragma unroll
    for (int w = 0; w < 16; ++w) {
      th += sredh[w];
      ta += sreda[w];
    }
    int k = 0;
    while (ta > 1.0 && k < 1100) {
      ta *= 0.5;
      ++k;
    }
    out[0] = ldexpf((float)th, -k);
  }
}

extern "C" void kernel_launch(void* const* d_in, const int* in_sizes, int n_in,
                              void* d_out, int out_size, void* d_ws, size_t ws_size,
                              hipStream_t stream) {
  const float* X = (const float*)d_in[0];
  const float* W = (const float*)d_in[1];
  const float* b = (const float*)d_in[2];
  const float* Wi = (const float*)d_in[3];
  float* out = (float*)d_out;
  float* wsf = (float*)d_ws;

  const int nrows = in_sizes[0] / D;  // 1,000,000

  hipLaunchKernelGGL(prep_kernel, dim3(1), dim3(1024), 0, stream, W, b, Wi, wsf);

  const int nthreads = (nrows + RPT - 1) / RPT;
  const int nblocks = (nthreads + NT - 1) / NT;  // 1954
  double* partials = (double*)(wsf + WS_PART_OFF);
  hipLaunchKernelGGL(fused_kernel, dim3(nblocks), dim3(NT), 0, stream,
                     X, b, wsf + WS_M1_OFF, wsf + WS_C_OFF, wsf + WS_WT_OFF,
                     partials, nrows);

  hipLaunchKernelGGL(fin_kernel, dim3(1), dim3(1024), 0, stream, partials, out,
                     nblocks);
}

// Round 9
// 129.845 us; speedup vs baseline: 1.4418x; 1.0282x over previous
//
#include <hip/hip_runtime.h>
#include <math.h>

#define D 20
#define NT 256
#define RPT 1  // one row per thread -> ~52 live VGPRs -> 8 waves/SIMD

// ws word offsets (16B-aligned):
//   [8..407]    M1tT[400]: [d][j] = sum_e W[e][d]*W_init[e][j]   (d-major)
//   [408..427]  c[20]:     c[j] = sum_e b[e]*W_init[e][j] + 1
//   [428..827]  Wt[400]:   [j][j2] = W[j2][j]                    (transposed)
//   [1024..]    partials: double2 per block (sum, sumabs)
#define WS_M1_OFF 8
#define WS_C_OFF 408
#define WS_WT_OFF 428
#define WS_PART_OFF 1024  // in floats -> byte 4096

__global__ void prep_kernel(const float* __restrict__ W,
                            const float* __restrict__ b,
                            const float* __restrict__ Wi,
                            float* __restrict__ wsf) {
  int t = threadIdx.x;  // 1024 threads
  if (t < D * D) {
    int d = t / D, j = t % D;
    float a = 0.f;
#pragma unroll
    for (int e = 0; e < D; ++e) a = fmaf(W[e * D + d], Wi[e * D + j], a);
    wsf[WS_M1_OFF + t] = a;
  } else if (t < 2 * D * D) {
    int i = t - D * D;
    int j = i / D, j2 = i % D;
    wsf[WS_WT_OFF + i] = W[j2 * D + j];
  } else if (t < 2 * D * D + D) {
    int j = t - 2 * D * D;
    float a = 1.0f;
#pragma unroll
    for (int e = 0; e < D; ++e) a = fmaf(b[e], Wi[e * D + j], a);
    wsf[WS_C_OFF + j] = a;
  }
}

// R8 structure (s_load constants from __restrict__ uniform pointers, upfront
// X float4 loads, rank-1 both stages, per-block partials, no atomics) at
// RPT=1: live set ~52 VGPRs fits the 64-VGPR occupancy step, so
// __launch_bounds__(256,8) gives 8 waves/SIMD — each s_load-chunk lgkmcnt
// stall is covered by 7 co-resident waves.
__global__ __launch_bounds__(NT, 8) void fused_kernel(
    const float* __restrict__ X,
    const float* __restrict__ bb_,
    const float* __restrict__ M1,   // d-major [d][j]
    const float* __restrict__ cc_,  // c[j]
    const float* __restrict__ Wt,   // j-major [j][j2]
    double* __restrict__ partials,
    int nrows) {
  const int t = threadIdx.x;

  const long long row = (long long)blockIdx.x * NT + t;
  const long long rmax = (long long)nrows - 1;
  const float valid = (row <= rmax) ? 1.0f : 0.0f;
  const long long r0 = (row <= rmax) ? row : rmax;

  // --- Issue all 5 X float4 loads immediately (one 80B row) ---
  const float4* __restrict__ Xv = (const float4*)(X + r0 * D);
  float4 xv[5];
#pragma unroll
  for (int s = 0; s < 5; ++s) xv[s] = Xv[s];

  float xa[D];
#pragma unroll
  for (int jv = 0; jv < 5; ++jv) {
    float4 v = xv[jv];
    xa[4 * jv + 0] = v.x;
    xa[4 * jv + 1] = v.y;
    xa[4 * jv + 2] = v.z;
    xa[4 * jv + 3] = v.w;
  }

  // --- Stage 1: h2 = x @ M1 + c (d-major rank-1, 20 indep accumulators) ---
  float h2[D];
#pragma unroll
  for (int j = 0; j < D; ++j) h2[j] = cc_[j];  // uniform -> s_load
#pragma unroll
  for (int d = 0; d < D; ++d) {
    const float xd = xa[d];
#pragma unroll
    for (int j = 0; j < D; ++j) {
      h2[j] = fmaf(xd, M1[d * D + j], h2[j]);  // uniform -> s_load
    }
  }

  // --- ReLU ---
#pragma unroll
  for (int j = 0; j < D; ++j) h2[j] = fmaxf(h2[j], 0.f);

  // --- Stage 2: h3 = h2 @ W^T + b (j-major rank-1 via Wt, 20 indep accs) ---
  float h3[D];
#pragma unroll
  for (int j2 = 0; j2 < D; ++j2) h3[j2] = bb_[j2];  // uniform -> s_load
#pragma unroll
  for (int j = 0; j < D; ++j) {
    const float p = h2[j];
#pragma unroll
    for (int j2 = 0; j2 < D; ++j2) {
      h3[j2] = fmaf(p, Wt[j * D + j2], h3[j2]);  // uniform -> s_load
    }
  }

  // --- Masked per-thread sums ---
  float rs = 0.f, ra = 0.f;
#pragma unroll
  for (int j = 0; j < D; ++j) {
    rs += h3[j];
    ra += fabsf(h3[j]);
  }
  rs *= valid;
  ra *= valid;

  // --- Wave shuffle reduce -> cross-wave LDS -> per-block slot ---
  __shared__ float sred[8];
#pragma unroll
  for (int off = 32; off > 0; off >>= 1) {
    rs += __shfl_down(rs, off, 64);
    ra += __shfl_down(ra, off, 64);
  }
  const int wave = t >> 6, lane = t & 63;
  if (lane == 0) {
    sred[wave] = rs;
    sred[4 + wave] = ra;
  }
  __syncthreads();
  if (t == 0) {
    float s1 = sred[0] + sred[1] + sred[2] + sred[3];
    float s2 = sred[4] + sred[5] + sred[6] + sred[7];
    partials[2 * blockIdx.x + 0] = (double)s1;
    partials[2 * blockIdx.x + 1] = (double)s2;
  }
}

// Reduce per-block partials, count halvings, write scalar output.
__global__ void fin_kernel(const double* __restrict__ partials,
                           float* __restrict__ out, int nblocks) {
  __shared__ double sredh[16], sreda[16];
  const int t = threadIdx.x;  // 1024 threads
  double sh = 0.0, sa = 0.0;
  for (int i = t; i < nblocks; i += 1024) {
    sh += partials[2 * i + 0];
    sa += partials[2 * i + 1];
  }
#pragma unroll
  for (int off = 32; off > 0; off >>= 1) {
    sh += __shfl_down(sh, off, 64);
    sa += __shfl_down(sa, off, 64);
  }
  const int wave = t >> 6, lane = t & 63;
  if (lane == 0) {
    sredh[wave] = sh;
    sreda[wave] = sa;
  }
  __syncthreads();
  if (t == 0) {
    double th = 0.0, ta = 0.0;
#pragma unroll
    for (int w = 0; w < 16; ++w) {
      th += sredh[w];
      ta += sreda[w];
    }
    int k = 0;
    while (ta > 1.0 && k < 1100) {
      ta *= 0.5;
      ++k;
    }
    out[0] = ldexpf((float)th, -k);
  }
}

extern "C" void kernel_launch(void* const* d_in, const int* in_sizes, int n_in,
                              void* d_out, int out_size, void* d_ws, size_t ws_size,
                              hipStream_t stream) {
  const float* X = (const float*)d_in[0];
  const float* W = (const float*)d_in[1];
  const float* b = (const float*)d_in[2];
  const float* Wi = (const float*)d_in[3];
  float* out = (float*)d_out;
  float* wsf = (float*)d_ws;

  const int nrows = in_sizes[0] / D;  // 1,000,000

  hipLaunchKernelGGL(prep_kernel, dim3(1), dim3(1024), 0, stream, W, b, Wi, wsf);

  const int nblocks = (nrows + NT - 1) / NT;  // 3907
  double* partials = (double*)(wsf + WS_PART_OFF);
  hipLaunchKernelGGL(fused_kernel, dim3(nblocks), dim3(NT), 0, stream,
                     X, b, wsf + WS_M1_OFF, wsf + WS_C_OFF, wsf + WS_WT_OFF,
                     partials, nrows);

  hipLaunchKernelGGL(fin_kernel, dim3(1), dim3(1024), 0, stream, partials, out,
                     nblocks);
}

// Round 10
// 127.081 us; speedup vs baseline: 1.4732x; 1.0218x over previous
//
#include <hip/hip_runtime.h>
#include <math.h>

#define D 20

typedef __attribute__((ext_vector_type(8))) __bf16 bf16x8;
typedef __attribute__((ext_vector_type(4))) float f32x4;

// ws byte layout:
//   [0,    2048)  fragB1: 2 tiles x 64 lanes x 8 bf16  (stage-1 B-fragments, M1 padded 32x32)
//   [2048, 4096)  fragB2: 2 tiles x 64 lanes x 8 bf16  (stage-2 B-fragments, W^T padded 32x32)
//   [4096, 4224)  cpad[32] fp32 (c[j] = sum_e b[e]*Wi[e][j] + 1, 0-padded)
//   [4224, 4352)  bpad[32] fp32 (b 0-padded)
//   [8192, ...)   partials: double2 per block (sum, sumabs), 15625 entries
#define WS_B1_BYTE 0
#define WS_B2_BYTE 2048
#define WS_C_BYTE 4096
#define WS_BB_BYTE 4224
#define WS_PART_BYTE 8192

__device__ __forceinline__ unsigned f2bf_u(float f) {  // fp32 -> bf16 bits (RTNE)
  unsigned u = __float_as_uint(f);
  u += 0x7fffu + ((u >> 16) & 1u);
  return u >> 16;
}

// Build B-fragments for both MFMA stages + padded biases.
// Fragment layout (mfma_f32_16x16x32_bf16): lane holds B[k][n] for
// n = lane&15 (+16*tile), k = (lane>>4)*8 + j, j=0..7. k,n >= 20 -> 0.
__global__ void prep_kernel(const float* __restrict__ W,
                            const float* __restrict__ b,
                            const float* __restrict__ Wi,
                            unsigned char* __restrict__ ws) {
  unsigned short* fb1 = (unsigned short*)(ws + WS_B1_BYTE);
  unsigned short* fb2 = (unsigned short*)(ws + WS_B2_BYTE);
  float* cpad = (float*)(ws + WS_C_BYTE);
  float* bpad = (float*)(ws + WS_BB_BYTE);

  const int t = threadIdx.x;  // 1024 threads
  {
    const int tile = t >> 9, rem = t & 511;
    const int lane = rem >> 3, j = rem & 7;
    const int k = (lane >> 4) * 8 + j;
    const int n = tile * 16 + (lane & 15);
    float v1 = 0.f, v2 = 0.f;
    if (k < D && n < D) {
      float a = 0.f;
#pragma unroll
      for (int e = 0; e < D; ++e) a = fmaf(W[e * D + k], Wi[e * D + n], a);
      v1 = a;                // M1[k][n]
      v2 = W[n * D + k];     // (W^T)[k][n]
    }
    fb1[t] = (unsigned short)f2bf_u(v1);
    fb2[t] = (unsigned short)f2bf_u(v2);
  }
  if (t < 32) {
    float cv = 0.f, bv = 0.f;
    if (t < D) {
      float a = 1.0f;
#pragma unroll
      for (int e = 0; e < D; ++e) a = fmaf(b[e], Wi[e * D + t], a);
      cv = a;
      bv = b[t];
    }
    cpad[t] = cv;
    bpad[t] = bv;
  }
}

// MFMA fused kernel: 256 threads = 4 waves, 16 rows/wave, 64 rows/block.
// Per wave: A1 from X (direct global, k-padded), 2 MFMA (stage 1, bias via
// C-init), relu, C-layout -> A-layout via LDS (stride-36 rows: 16B-aligned,
// max 2-way bank aliasing = free), 2 MFMA (stage 2), sums. Padded B-frag
// cols are zero so invalid columns self-annihilate -> no masks anywhere.
__global__ __launch_bounds__(256, 4) void fused_kernel(
    const float* __restrict__ X,
    const unsigned char* __restrict__ ws,
    double* __restrict__ partials) {
  __shared__ __align__(16) float sP[4 * 16 * 36];  // 9216 B
  __shared__ float sred[8];

  const uint4* __restrict__ fb1 = (const uint4*)(ws + WS_B1_BYTE);
  const uint4* __restrict__ fb2 = (const uint4*)(ws + WS_B2_BYTE);
  const float* __restrict__ cpad = (const float*)(ws + WS_C_BYTE);
  const float* __restrict__ bpad = (const float*)(ws + WS_BB_BYTE);

  const int t = threadIdx.x;
  const int wave = t >> 6, lane = t & 63;
  const int m = lane & 15, oct = lane >> 4;
  const long long rowg = (long long)blockIdx.x * 64 + wave * 16 + m;

  // ---- A1 fragment: X[rowg][k0..k0+7], zero-padded past k=19 ----
  const int k0 = oct * 8;
  const long long o1 = rowg * D + (long long)(k0 < D ? k0 : 0);
  const long long o2 = rowg * D + (long long)(k0 + 4 < D ? k0 + 4 : 0);
  float4 v1 = *(const float4*)(X + o1);
  float4 v2 = *(const float4*)(X + o2);
  const float s1m = (k0 < D) ? 1.f : 0.f;      // whole-float4 validity
  const float s2m = (k0 + 4 < D) ? 1.f : 0.f;

  union UF { bf16x8 v; unsigned u[4]; } a1;
  a1.u[0] = f2bf_u(v1.x * s1m) | (f2bf_u(v1.y * s1m) << 16);
  a1.u[1] = f2bf_u(v1.z * s1m) | (f2bf_u(v1.w * s1m) << 16);
  a1.u[2] = f2bf_u(v2.x * s2m) | (f2bf_u(v2.y * s2m) << 16);
  a1.u[3] = f2bf_u(v2.z * s2m) | (f2bf_u(v2.w * s2m) << 16);

  union UB { bf16x8 v; uint4 q; } b10, b11, b20, b21;
  b10.q = fb1[0 * 64 + lane];
  b11.q = fb1[1 * 64 + lane];
  b20.q = fb2[0 * 64 + lane];
  b21.q = fb2[1 * 64 + lane];

  // ---- Stage 1 MFMA, bias folded into C-init ----
  const float c0 = cpad[m], c1 = cpad[16 + m];
  f32x4 acc0 = {c0, c0, c0, c0};
  f32x4 acc1 = {c1, c1, c1, c1};
  acc0 = __builtin_amdgcn_mfma_f32_16x16x32_bf16(a1.v, b10.v, acc0, 0, 0, 0);
  acc1 = __builtin_amdgcn_mfma_f32_16x16x32_bf16(a1.v, b11.v, acc1, 0, 0, 0);

  // ---- relu + C-layout -> LDS (cols 16..31 of tile1 write the zero pad) ----
  float* wp = sP + wave * 576;
#pragma unroll
  for (int i = 0; i < 4; ++i) {
    wp[(4 * oct + i) * 36 + m] = fmaxf(acc0[i], 0.f);
    wp[(4 * oct + i) * 36 + 16 + m] = fmaxf(acc1[i], 0.f);
  }
  __syncthreads();

  // ---- A2 fragment from LDS (rows stride 36 -> 16B-aligned b128 reads) ----
  const float4* rp = (const float4*)(wp + m * 36 + k0);
  float4 p1 = rp[0], p2 = rp[1];
  union UF a2;
  a2.u[0] = f2bf_u(p1.x) | (f2bf_u(p1.y) << 16);
  a2.u[1] = f2bf_u(p1.z) | (f2bf_u(p1.w) << 16);
  a2.u[2] = f2bf_u(p2.x) | (f2bf_u(p2.y) << 16);
  a2.u[3] = f2bf_u(p2.z) | (f2bf_u(p2.w) << 16);

  // ---- Stage 2 MFMA, bias folded into C-init ----
  const float bb0 = bpad[m], bb1 = bpad[16 + m];
  f32x4 d0 = {bb0, bb0, bb0, bb0};
  f32x4 d1 = {bb1, bb1, bb1, bb1};
  d0 = __builtin_amdgcn_mfma_f32_16x16x32_bf16(a2.v, b20.v, d0, 0, 0, 0);
  d1 = __builtin_amdgcn_mfma_f32_16x16x32_bf16(a2.v, b21.v, d1, 0, 0, 0);

  // ---- Sums (padded cols of d1 are exactly 0 -> no masking) ----
  float rs = 0.f, ra = 0.f;
#pragma unroll
  for (int i = 0; i < 4; ++i) {
    rs += d0[i] + d1[i];
    ra += fabsf(d0[i]) + fabsf(d1[i]);
  }

  // ---- Wave shuffle reduce -> cross-wave LDS -> per-block slot ----
#pragma unroll
  for (int off = 32; off > 0; off >>= 1) {
    rs += __shfl_down(rs, off, 64);
    ra += __shfl_down(ra, off, 64);
  }
  if (lane == 0) {
    sred[wave] = rs;
    sred[4 + wave] = ra;
  }
  __syncthreads();
  if (t == 0) {
    float s1 = sred[0] + sred[1] + sred[2] + sred[3];
    float s2 = sred[4] + sred[5] + sred[6] + sred[7];
    partials[2 * blockIdx.x + 0] = (double)s1;
    partials[2 * blockIdx.x + 1] = (double)s2;
  }
}

// Reduce per-block partials, count halvings, write scalar output.
__global__ void fin_kernel(const double* __restrict__ partials,
                           float* __restrict__ out, int nblocks) {
  __shared__ double sredh[16], sreda[16];
  const int t = threadIdx.x;  // 1024 threads
  double sh = 0.0, sa = 0.0;
  for (int i = t; i < nblocks; i += 1024) {
    sh += partials[2 * i + 0];
    sa += partials[2 * i + 1];
  }
#pragma unroll
  for (int off = 32; off > 0; off >>= 1) {
    sh += __shfl_down(sh, off, 64);
    sa += __shfl_down(sa, off, 64);
  }
  const int wave = t >> 6, lane = t & 63;
  if (lane == 0) {
    sredh[wave] = sh;
    sreda[wave] = sa;
  }
  __syncthreads();
  if (t == 0) {
    double th = 0.0, ta = 0.0;
#pragma unroll
    for (int w = 0; w < 16; ++w) {
      th += sredh[w];
      ta += sreda[w];
    }
    int k = 0;
    while (ta > 1.0 && k < 1100) {
      ta *= 0.5;
      ++k;
    }
    out[0] = ldexpf((float)th, -k);
  }
}

extern "C" void kernel_launch(void* const* d_in, const int* in_sizes, int n_in,
                              void* d_out, int out_size, void* d_ws, size_t ws_size,
                              hipStream_t stream) {
  const float* X = (const float*)d_in[0];
  const float* W = (const float*)d_in[1];
  const float* b = (const float*)d_in[2];
  const float* Wi = (const float*)d_in[3];
  float* out = (float*)d_out;
  unsigned char* ws = (unsigned char*)d_ws;

  const int nrows = in_sizes[0] / D;       // 1,000,000
  const int nblocks = nrows / 64;          // 15625 exactly (no tail)
  double* partials = (double*)(ws + WS_PART_BYTE);

  hipLaunchKernelGGL(prep_kernel, dim3(1), dim3(1024), 0, stream, W, b, Wi, ws);
  hipLaunchKernelGGL(fused_kernel, dim3(nblocks), dim3(256), 0, stream,
                     X, ws, partials);
  hipLaunchKernelGGL(fin_kernel, dim3(1), dim3(1024), 0, stream, partials, out,
                     nblocks);
}

// Round 11
// 120.818 us; speedup vs baseline: 1.5495x; 1.0518x over previous
//
#include <hip/hip_runtime.h>
#include <math.h>

#define D 20
#define ITER 5  // 16-row tiles per wave; 4 waves * 5 * 16 = 320 rows/block

typedef __attribute__((ext_vector_type(8))) __bf16 bf16x8;
typedef __attribute__((ext_vector_type(4))) float f32x4;

// ws byte layout:
//   [0,    2048)  fragB1: 2 tiles x 64 lanes x 8 bf16  (stage-1 B, M1 padded 32x32)
//   [2048, 4096)  fragB2: 2 tiles x 64 lanes x 8 bf16  (stage-2 B, W^T padded 32x32)
//   [4096, 4224)  cpad[32] fp32 (c = b@Wi + 1, 0-padded)
//   [4224, 4352)  bpad[32] fp32 (b, 0-padded)
//   [8192, ...)   partials: double2 per block, 3125 entries
#define WS_B1_BYTE 0
#define WS_B2_BYTE 2048
#define WS_C_BYTE 4096
#define WS_BB_BYTE 4224
#define WS_PART_BYTE 8192

__device__ __forceinline__ unsigned f2bf_u(float f) {  // fp32 -> bf16 bits (RTNE)
  unsigned u = __float_as_uint(f);
  u += 0x7fffu + ((u >> 16) & 1u);
  return u >> 16;
}

// Build B-fragments for both MFMA stages + padded biases (layout verified R10).
__global__ void prep_kernel(const float* __restrict__ W,
                            const float* __restrict__ b,
                            const float* __restrict__ Wi,
                            unsigned char* __restrict__ ws) {
  unsigned short* fb1 = (unsigned short*)(ws + WS_B1_BYTE);
  unsigned short* fb2 = (unsigned short*)(ws + WS_B2_BYTE);
  float* cpad = (float*)(ws + WS_C_BYTE);
  float* bpad = (float*)(ws + WS_BB_BYTE);

  const int t = threadIdx.x;  // 1024 threads
  {
    const int tile = t >> 9, rem = t & 511;
    const int lane = rem >> 3, j = rem & 7;
    const int k = (lane >> 4) * 8 + j;
    const int n = tile * 16 + (lane & 15);
    float v1 = 0.f, v2 = 0.f;
    if (k < D && n < D) {
      float a = 0.f;
#pragma unroll
      for (int e = 0; e < D; ++e) a = fmaf(W[e * D + k], Wi[e * D + n], a);
      v1 = a;             // M1[k][n]
      v2 = W[n * D + k];  // (W^T)[k][n]
    }
    fb1[t] = (unsigned short)f2bf_u(v1);
    fb2[t] = (unsigned short)f2bf_u(v2);
  }
  if (t < 32) {
    float cv = 0.f, bv = 0.f;
    if (t < D) {
      float a = 1.0f;
#pragma unroll
      for (int e = 0; e < D; ++e) a = fmaf(b[e], Wi[e * D + t], a);
      cv = a;
      bv = b[t];
    }
    cpad[t] = cv;
    bpad[t] = bv;
  }
}

// MFMA fused kernel, multi-tile: 4 waves x 5 tiles x 16 rows = 320 rows/block,
// grid 3125 (exact, no tail). Constants once per wave; one reduction/block.
// Transpose uses the wave's private LDS region (in-order DS pipe within a
// wave -> no cross-wave barrier needed). Next tile's X prefetched.
__global__ __launch_bounds__(256, 4) void fused_kernel(
    const float* __restrict__ X,
    const unsigned char* __restrict__ ws,
    double* __restrict__ partials) {
  __shared__ __align__(16) float sP[4 * 16 * 36];  // 9216 B, per-wave 576 floats
  __shared__ float sred[8];

  const uint4* __restrict__ fb1 = (const uint4*)(ws + WS_B1_BYTE);
  const uint4* __restrict__ fb2 = (const uint4*)(ws + WS_B2_BYTE);
  const float* __restrict__ cpad = (const float*)(ws + WS_C_BYTE);
  const float* __restrict__ bpad = (const float*)(ws + WS_BB_BYTE);

  const int t = threadIdx.x;
  const int wave = t >> 6, lane = t & 63;
  const int m = lane & 15, oct = lane >> 4;
  const int k0 = oct * 8;
  const int ko1 = (k0 < D) ? k0 : 0;          // clamped k-offsets (in-bounds)
  const int ko2 = (k0 + 4 < D) ? k0 + 4 : 0;
  const float s1m = (k0 < D) ? 1.f : 0.f;     // float4 validity masks
  const float s2m = (k0 + 4 < D) ? 1.f : 0.f;

  // --- Per-wave constants (once) ---
  union UB { bf16x8 v; uint4 q; } b10, b11, b20, b21;
  b10.q = fb1[0 * 64 + lane];
  b11.q = fb1[1 * 64 + lane];
  b20.q = fb2[0 * 64 + lane];
  b21.q = fb2[1 * 64 + lane];
  const float c0 = cpad[m], c1 = cpad[16 + m];
  const float bb0 = bpad[m], bb1 = bpad[16 + m];

  float* wp = sP + wave * 576;
  const float4* rp = (const float4*)(wp + m * 36 + k0);

  const long long wavebase = (long long)blockIdx.x * (4 * ITER * 16) + wave * (ITER * 16);

  float rs = 0.f, ra = 0.f;

  // Prefetch tile 0's X.
  long long rowg = wavebase + m;
  float4 v1 = *(const float4*)(X + rowg * D + ko1);
  float4 v2 = *(const float4*)(X + rowg * D + ko2);

#pragma unroll
  for (int it = 0; it < ITER; ++it) {
    float4 n1, n2;
    if (it + 1 < ITER) {  // compile-time (unrolled): prefetch next tile
      const long long rn = wavebase + (it + 1) * 16 + m;
      n1 = *(const float4*)(X + rn * D + ko1);
      n2 = *(const float4*)(X + rn * D + ko2);
    }

    // A1 fragment (k-padded with zeros).
    union UF { bf16x8 v; unsigned u[4]; } a1;
    a1.u[0] = f2bf_u(v1.x * s1m) | (f2bf_u(v1.y * s1m) << 16);
    a1.u[1] = f2bf_u(v1.z * s1m) | (f2bf_u(v1.w * s1m) << 16);
    a1.u[2] = f2bf_u(v2.x * s2m) | (f2bf_u(v2.y * s2m) << 16);
    a1.u[3] = f2bf_u(v2.z * s2m) | (f2bf_u(v2.w * s2m) << 16);

    // Stage 1 MFMA, bias in C-init.
    f32x4 acc0 = {c0, c0, c0, c0};
    f32x4 acc1 = {c1, c1, c1, c1};
    acc0 = __builtin_amdgcn_mfma_f32_16x16x32_bf16(a1.v, b10.v, acc0, 0, 0, 0);
    acc1 = __builtin_amdgcn_mfma_f32_16x16x32_bf16(a1.v, b11.v, acc1, 0, 0, 0);

    // relu + C-layout -> wave-private LDS (stride-36 rows; 0 conflicts @R10).
#pragma unroll
    for (int i = 0; i < 4; ++i) {
      wp[(4 * oct + i) * 36 + m] = fmaxf(acc0[i], 0.f);
      wp[(4 * oct + i) * 36 + 16 + m] = fmaxf(acc1[i], 0.f);
    }
    // Same-wave DS ops are processed in order -> read sees the writes.
    float4 p1 = rp[0], p2 = rp[1];

    union UF a2;
    a2.u[0] = f2bf_u(p1.x) | (f2bf_u(p1.y) << 16);
    a2.u[1] = f2bf_u(p1.z) | (f2bf_u(p1.w) << 16);
    a2.u[2] = f2bf_u(p2.x) | (f2bf_u(p2.y) << 16);
    a2.u[3] = f2bf_u(p2.z) | (f2bf_u(p2.w) << 16);

    // Stage 2 MFMA, bias in C-init.
    f32x4 d0 = {bb0, bb0, bb0, bb0};
    f32x4 d1 = {bb1, bb1, bb1, bb1};
    d0 = __builtin_amdgcn_mfma_f32_16x16x32_bf16(a2.v, b20.v, d0, 0, 0, 0);
    d1 = __builtin_amdgcn_mfma_f32_16x16x32_bf16(a2.v, b21.v, d1, 0, 0, 0);

    // Sums (padded cols are exact zeros -> no masking).
#pragma unroll
    for (int i = 0; i < 4; ++i) {
      rs += d0[i] + d1[i];
      ra += fabsf(d0[i]) + fabsf(d1[i]);
    }

    if (it + 1 < ITER) {
      v1 = n1;
      v2 = n2;
    }
  }

  // --- Wave shuffle reduce -> cross-wave LDS -> per-block slot ---
#pragma unroll
  for (int off = 32; off > 0; off >>= 1) {
    rs += __shfl_down(rs, off, 64);
    ra += __shfl_down(ra, off, 64);
  }
  if (lane == 0) {
    sred[wave] = rs;
    sred[4 + wave] = ra;
  }
  __syncthreads();
  if (t == 0) {
    float s1 = sred[0] + sred[1] + sred[2] + sred[3];
    float s2 = sred[4] + sred[5] + sred[6] + sred[7];
    partials[2 * blockIdx.x + 0] = (double)s1;
    partials[2 * blockIdx.x + 1] = (double)s2;
  }
}

// Reduce per-block partials, count halvings, write scalar output.
__global__ void fin_kernel(const double* __restrict__ partials,
                           float* __restrict__ out, int nblocks) {
  __shared__ double sredh[16], sreda[16];
  const int t = threadIdx.x;  // 1024 threads
  double sh = 0.0, sa = 0.0;
  for (int i = t; i < nblocks; i += 1024) {
    sh += partials[2 * i + 0];
    sa += partials[2 * i + 1];
  }
#pragma unroll
  for (int off = 32; off > 0; off >>= 1) {
    sh += __shfl_down(sh, off, 64);
    sa += __shfl_down(sa, off, 64);
  }
  const int wave = t >> 6, lane = t & 63;
  if (lane == 0) {
    sredh[wave] = sh;
    sreda[wave] = sa;
  }
  __syncthreads();
  if (t == 0) {
    double th = 0.0, ta = 0.0;
#pragma unroll
    for (int w = 0; w < 16; ++w) {
      th += sredh[w];
      ta += sreda[w];
    }
    int k = 0;
    while (ta > 1.0 && k < 1100) {
      ta *= 0.5;
      ++k;
    }
    out[0] = ldexpf((float)th, -k);
  }
}

extern "C" void kernel_launch(void* const* d_in, const int* in_sizes, int n_in,
                              void* d_out, int out_size, void* d_ws, size_t ws_size,
                              hipStream_t stream) {
  const float* X = (const float*)d_in[0];
  const float* W = (const float*)d_in[1];
  const float* b = (const float*)d_in[2];
  const float* Wi = (const float*)d_in[3];
  float* out = (float*)d_out;
  unsigned char* ws = (unsigned char*)d_ws;

  const int nrows = in_sizes[0] / D;            // 1,000,000
  const int nblocks = nrows / (4 * ITER * 16);  // 3125 exactly, no tail
  double* partials = (double*)(ws + WS_PART_BYTE);

  hipLaunchKernelGGL(prep_kernel, dim3(1), dim3(1024), 0, stream, W, b, Wi, ws);
  hipLaunchKernelGGL(fused_kernel, dim3(nblocks), dim3(256), 0, stream,
                     X, ws, partials);
  hipLaunchKernelGGL(fin_kernel, dim3(1), dim3(1024), 0, stream, partials, out,
                     nblocks);
}